// Round 18
// baseline (246.637 us; speedup 1.0000x reference)
//
#include <hip/hip_runtime.h>
#include <stdint.h>

// Problem constants
#define KCB 4096
#define DIM 128
#define BSZ 8
#define TLEN 3000
#define NPT 24000            // BSZ*TLEN
#define KD (KCB*DIM)         // 524288
#define BDT (BSZ*DIM*TLEN)   // 3072000

// Output layout (floats, concatenated in reference return order)
#define OFF_ZQ    0
#define OFF_CODES 3072000
#define OFF_LOSS  3096000
#define OFF_CB    3096001
#define OFF_CS    3620289
#define OFF_EA    3624385

// Big scratch in d_out regions that are dead until later kernels:
//   zh/zl  -> z_q region (holds -2*z split; z_q written by zq_loss later)
//   cbh/cbl-> new_codebook region (PRE-SWIZZLED chunks; finalize writes LAST)
#define OUT_ZH    0
#define OUT_ZL    1536000
#define OUT_CBH   3096004
#define OUT_CBL   3358148

// Workspace layout (float units) — total ~873 KB (R3 proved >=930 KB usable)
#define WS_LOSS   0
#define WS_NTOT   1
#define WS_COUNTS 16                     // 4096
#define WS_Y2     (WS_COUNTS + 4096)     // 4096
#define WS_X2     (WS_Y2 + 4096)         // 24000
#define WS_CS0    (WS_X2 + 24000)        // 4096
#define WS_RAND   (WS_CS0 + 4096)        // uint32[4096]
#define WS_IDX    (WS_RAND + 4096)       // int32[24000]
#define WS_RCNT   (WS_IDX + 24000)       // int32[1] (+pad to 16)
#define WS_RLIST  (WS_RCNT + 16)         // int32[RCAP*10]
#define RCAP      8192
#define WS_PBV    (WS_RLIST + RCAP*10)   // float[2*NPT] per-half approx min
#define WS_PBK    (WS_PBV + 2*NPT)       // int[2*NPT]   per-half EXACT winner

#define EPS_CAND 2e-3f
#define CAND_MAX 8

typedef __attribute__((ext_vector_type(8))) short bf16x8;
typedef __attribute__((ext_vector_type(4))) float f32x4;
typedef __attribute__((ext_vector_type(4))) int i32x4;

__device__ __forceinline__ unsigned short f2bf(float f) {
  uint32_t u = __float_as_uint(f);
  uint32_t r = (u + 0x7FFFu + ((u >> 16) & 1u)) >> 16;   // RNE
  return (unsigned short)r;
}
__device__ __forceinline__ float bf2f(unsigned short h) {
  return __uint_as_float(((uint32_t)h) << 16);
}

// async global->LDS DMA, 16 B per lane; LDS dest = wave-uniform base + lane*16
__device__ __forceinline__ void async16(const void* g, void* l) {
  __builtin_amdgcn_global_load_lds(
      (const __attribute__((address_space(1))) void*)g,
      (__attribute__((address_space(3))) void*)l, 16, 0, 0);
}

// ---------------- threefry2x32-20 (JAX-compatible) ----------------
__device__ __forceinline__ void threefry2x32(uint32_t k0, uint32_t k1,
                                             uint32_t x0, uint32_t x1,
                                             uint32_t& o0, uint32_t& o1) {
  const uint32_t ks0 = k0, ks1 = k1, ks2 = k0 ^ k1 ^ 0x1BD11BDAu;
  const int r0[4] = {13, 15, 26, 6};
  const int r1[4] = {17, 29, 16, 24};
  x0 += ks0; x1 += ks1;
  #pragma unroll
  for (int i = 0; i < 5; ++i) {
    #pragma unroll
    for (int j = 0; j < 4; ++j) {
      int r = (i & 1) ? r1[j] : r0[j];
      x0 += x1;
      x1 = (x1 << r) | (x1 >> (32 - r));
      x1 ^= x0;
    }
    uint32_t ia = (uint32_t)((i + 1) % 3), ib = (uint32_t)((i + 2) % 3);
    uint32_t a = (ia == 0) ? ks0 : (ia == 1) ? ks1 : ks2;
    uint32_t b = (ib == 0) ? ks0 : (ib == 1) ? ks1 : ks2;
    x0 += a;
    x1 += b + (uint32_t)(i + 1);
  }
  o0 = x0; o1 = x1;
}

// numpy pairwise sum-of-squares, n=128
__device__ __forceinline__ float np_sumsq_128(const float* __restrict__ v) {
  float r[8];
  #pragma unroll
  for (int j = 0; j < 8; ++j) r[j] = __fmul_rn(v[j], v[j]);
  #pragma unroll
  for (int i = 8; i < DIM; i += 8) {
    #pragma unroll
    for (int j = 0; j < 8; ++j)
      r[j] = __fadd_rn(r[j], __fmul_rn(v[i + j], v[i + j]));
  }
  return __fadd_rn(__fadd_rn(__fadd_rn(r[0], r[1]), __fadd_rn(r[2], r[3])),
                   __fadd_rn(__fadd_rn(r[4], r[5]), __fadd_rn(r[6], r[7])));
}

// exact np-fp32 distance: fl(fl(x2+y2) - 2*dot), serial ascending-d FMA dot
__device__ __forceinline__ float np_exact_dist(const float* __restrict__ zr,
                                               const float* __restrict__ cr,
                                               float x2v, float y2v) {
  float dot = 0.f;
  for (int d = 0; d < DIM; ++d)
    dot = __fmaf_rn(zr[(size_t)d * TLEN], cr[d], dot);
  float tt = __fadd_rn(x2v, y2v);
  return __fsub_rn(tt, __fmul_rn(2.0f, dot));
}

// ---------------- prep_z: transpose z -> bf16 hi/lo of (-2*z) + np-exact x2 -
__global__ void prep_z_kernel(const float* __restrict__ z,
                              unsigned short* __restrict__ zh,
                              unsigned short* __restrict__ zl,
                              float* __restrict__ x2) {
  __shared__ float zt[64 * 132];
  const int tid = threadIdx.x;
  const int n0 = blockIdx.x * 64;
  {
    int nl = tid & 63, dd = tid >> 6;
    int n = n0 + nl;
    int b = n / TLEN, t = n - b * TLEN;
    const float* zbase = z + (size_t)b * (DIM * TLEN) + t;
    #pragma unroll
    for (int d = dd; d < DIM; d += 4) zt[nl * 132 + d] = zbase[(size_t)d * TLEN];
  }
  __syncthreads();
  if (tid < 64) x2[n0 + tid] = np_sumsq_128(zt + tid * 132);   // on ORIGINAL z

  int r = tid >> 2, d0 = (tid & 3) * 32;
  const float* src = zt + r * 132 + d0;
  size_t base = (size_t)(n0 + r) * 128 + d0;
  #pragma unroll
  for (int c = 0; c < 4; ++c) {
    i32x4 wh, wl;
    #pragma unroll
    for (int q = 0; q < 4; ++q) {
      float f0 = -2.0f * src[c * 8 + q * 2], f1 = -2.0f * src[c * 8 + q * 2 + 1];
      unsigned short h0 = f2bf(f0), h1 = f2bf(f1);
      unsigned short l0 = f2bf(f0 - bf2f(h0)), l1 = f2bf(f1 - bf2f(h1));
      wh[q] = (int)((uint32_t)h0 | ((uint32_t)h1 << 16));
      wl[q] = (int)((uint32_t)l0 | ((uint32_t)l1 << 16));
    }
    *(i32x4*)(zh + base + c * 8) = wh;
    *(i32x4*)(zl + base + c * 8) = wl;
  }
}

// ---------------- prep_cb: bf16 hi/lo, chunks PRE-SWIZZLED (c ^= k&7) -------
__global__ void prep_cb_kernel(const float* __restrict__ cb,
                               unsigned short* __restrict__ cbh,
                               unsigned short* __restrict__ cbl,
                               float* __restrict__ y2) {
  int k = blockIdx.x * 256 + threadIdx.x;
  const float4* row4 = (const float4*)(cb + (size_t)k * DIM);
  float racc[8];
  #pragma unroll
  for (int j = 0; j < 8; ++j) racc[j] = 0.f;
  #pragma unroll 4
  for (int c2 = 0; c2 < 16; ++c2) {
    float4 a = row4[c2 * 2], b = row4[c2 * 2 + 1];
    float f[8] = {a.x, a.y, a.z, a.w, b.x, b.y, b.z, b.w};
    i32x4 wh, wl;
    #pragma unroll
    for (int q = 0; q < 4; ++q) {
      float f0 = f[q * 2], f1 = f[q * 2 + 1];
      unsigned short h0 = f2bf(f0), h1 = f2bf(f1);
      unsigned short l0 = f2bf(f0 - bf2f(h0)), l1 = f2bf(f1 - bf2f(h1));
      wh[q] = (int)((uint32_t)h0 | ((uint32_t)h1 << 16));
      wl[q] = (int)((uint32_t)l0 | ((uint32_t)l1 << 16));
    }
    int cs = c2 ^ (k & 7);                 // pre-swizzled chunk slot
    *(i32x4*)(cbh + (size_t)k * DIM + cs * 8) = wh;
    *(i32x4*)(cbl + (size_t)k * DIM + cs * 8) = wl;
    #pragma unroll
    for (int j = 0; j < 8; ++j)
      racc[j] = __fadd_rn(racc[j], __fmul_rn(f[j], f[j]));
  }
  y2[k] = __fadd_rn(__fadd_rn(__fadd_rn(racc[0], racc[1]), __fadd_rn(racc[2], racc[3])),
                    __fadd_rn(__fadd_rn(racc[4], racc[5]), __fadd_rn(racc[6], racc[7])));
}

// ---------------- ea_init ----------------
__global__ void ea_init_kernel(const float* __restrict__ ema_ea, float* __restrict__ out_ea) {
  int i = blockIdx.x * 256 + threadIdx.x;
  out_ea[i] = 0.99f * ema_ea[i];
}

// ---------------- MFMA argmin: K-split halves, 48 KB LDS -> 3 blocks/CU ----
// grid (375, 2) x 128 thr (2 waves, each 32k x 32n — R17's proven geometry).
// Per block: 64n rows x 2048 k (64 stages of 32k, DMA-staged). Output per
// row: approx local min bv + EXACT local first-occurrence winner (in-block
// np-exact rescore for rare local ties). merge_kernel resolves halves:
// margin > EPS decides outright (EPS >= 2*approx-error); else the global
// argmin is provably one of the two half-winners -> rlist exact rescore.
__launch_bounds__(128)
__global__ void mfma_argmin_kernel(const unsigned short* __restrict__ zh,
                                   const unsigned short* __restrict__ zl,
                                   const unsigned short* __restrict__ cbh,
                                   const unsigned short* __restrict__ cbl,
                                   const float* __restrict__ y2g,
                                   const float* __restrict__ x2g,
                                   const float* __restrict__ z,
                                   const float* __restrict__ cb,
                                   float* __restrict__ pbv,
                                   int* __restrict__ pbk) {
  __shared__ alignas(16) unsigned short zh_t[64 * 128];   // 16 KB, swizzled
  __shared__ alignas(16) unsigned short zl_t[64 * 128];   // 16 KB
  __shared__ alignas(16) unsigned short Ah_t[32 * 128];   // 8 KB (reused for lists)
  __shared__ alignas(16) unsigned short Al_t[32 * 128];   // 8 KB

  const int tid = threadIdx.x;
  const int wv = tid >> 6, lane = tid & 63;
  const int nw = wv;                       // wave owns n-half of the 64 rows
  const int lg = lane >> 4, lc = lane & 15;
  const int n0 = blockIdx.x * 64;
  const int hy = blockIdx.y;               // k-half
  const size_t kofs = (size_t)hy * 2048;   // first k row of this half

  // issue stage-0 DMA first (overlaps with z staging)
  {
    const char* gh = (const char*)cbh + kofs * 256 + (size_t)wv * 4096 + lane * 16;
    const char* gl_ = (const char*)cbl + kofs * 256 + (size_t)wv * 4096 + lane * 16;
    char* lh = (char*)Ah_t + wv * 4096;
    char* ll = (char*)Al_t + wv * 4096;
    #pragma unroll
    for (int i = 0; i < 4; ++i) {
      async16(gh + i * 1024, lh + i * 1024);
      async16(gl_ + i * 1024, ll + i * 1024);
    }
  }

  // stage 64 z rows hi/lo into LDS once (chunk = 16B; swizzle cc = c ^ (r&7))
  {
    int r = tid >> 1, c0 = (tid & 1) * 8;
    const i32x4* gzh = (const i32x4*)(zh + (size_t)(n0 + r) * 128);
    const i32x4* gzl = (const i32x4*)(zl + (size_t)(n0 + r) * 128);
    #pragma unroll
    for (int c = 0; c < 8; ++c) {
      int cc = (c0 + c) ^ (r & 7);
      ((i32x4*)zh_t)[r * 16 + cc] = gzh[c0 + c];
      ((i32x4*)zl_t)[r * 16 + cc] = gzl[c0 + c];
    }
  }

  float t1v[2], t2v[2], t3v[2];
  int   t1i[2], t2i[2], t3i[2];
  #pragma unroll
  for (int ns = 0; ns < 2; ++ns) {
    t1v[ns] = t2v[ns] = t3v[ns] = 3.402823466e+38f;
    t1i[ns] = t2i[ns] = t3i[ns] = 0x7FFFFFFF;
  }

  const int arow0 = lc, arow1 = 16 + lc;                 // A rows within stage
  const int zrow0 = nw * 32 + lc, zrow1 = nw * 32 + 16 + lc;

  for (int st = 0; st < 64; ++st) {
    asm volatile("s_waitcnt vmcnt(0)" ::: "memory");
    __syncthreads();                      // stage data ready

    const int kb = (int)kofs + st * 32;
    float4 y40 = *(const float4*)(y2g + kb + lg * 4);
    float4 y41 = *(const float4*)(y2g + kb + 16 + lg * 4);
    f32x4 acc[2][2];                      // [ks][ns]
    #pragma unroll
    for (int ns = 0; ns < 2; ++ns) {
      acc[0][ns][0] = y40.x; acc[0][ns][1] = y40.y; acc[0][ns][2] = y40.z; acc[0][ns][3] = y40.w;
      acc[1][ns][0] = y41.x; acc[1][ns][1] = y41.y; acc[1][ns][2] = y41.z; acc[1][ns][3] = y41.w;
    }

    #pragma unroll
    for (int ds = 0; ds < 4; ++ds) {
      int cA0 = (ds * 4 + lg) ^ (arow0 & 7);
      int cA1 = (ds * 4 + lg) ^ (arow1 & 7);
      bf16x8 a0h = *(const bf16x8*)&Ah_t[arow0 * 128 + cA0 * 8];
      bf16x8 a0l = *(const bf16x8*)&Al_t[arow0 * 128 + cA0 * 8];
      bf16x8 a1h = *(const bf16x8*)&Ah_t[arow1 * 128 + cA1 * 8];
      bf16x8 a1l = *(const bf16x8*)&Al_t[arow1 * 128 + cA1 * 8];
      int cz0 = (ds * 4 + lg) ^ (zrow0 & 7);
      int cz1 = (ds * 4 + lg) ^ (zrow1 & 7);
      bf16x8 z0h = *(const bf16x8*)&zh_t[zrow0 * 128 + cz0 * 8];
      bf16x8 z0l = *(const bf16x8*)&zl_t[zrow0 * 128 + cz0 * 8];
      bf16x8 z1h = *(const bf16x8*)&zh_t[zrow1 * 128 + cz1 * 8];
      bf16x8 z1l = *(const bf16x8*)&zl_t[zrow1 * 128 + cz1 * 8];
      acc[0][0] = __builtin_amdgcn_mfma_f32_16x16x32_bf16(a0h, z0h, acc[0][0], 0, 0, 0);
      acc[0][0] = __builtin_amdgcn_mfma_f32_16x16x32_bf16(a0h, z0l, acc[0][0], 0, 0, 0);
      acc[0][0] = __builtin_amdgcn_mfma_f32_16x16x32_bf16(a0l, z0h, acc[0][0], 0, 0, 0);
      acc[0][1] = __builtin_amdgcn_mfma_f32_16x16x32_bf16(a0h, z1h, acc[0][1], 0, 0, 0);
      acc[0][1] = __builtin_amdgcn_mfma_f32_16x16x32_bf16(a0h, z1l, acc[0][1], 0, 0, 0);
      acc[0][1] = __builtin_amdgcn_mfma_f32_16x16x32_bf16(a0l, z1h, acc[0][1], 0, 0, 0);
      acc[1][0] = __builtin_amdgcn_mfma_f32_16x16x32_bf16(a1h, z0h, acc[1][0], 0, 0, 0);
      acc[1][0] = __builtin_amdgcn_mfma_f32_16x16x32_bf16(a1h, z0l, acc[1][0], 0, 0, 0);
      acc[1][0] = __builtin_amdgcn_mfma_f32_16x16x32_bf16(a1l, z0h, acc[1][0], 0, 0, 0);
      acc[1][1] = __builtin_amdgcn_mfma_f32_16x16x32_bf16(a1h, z1h, acc[1][1], 0, 0, 0);
      acc[1][1] = __builtin_amdgcn_mfma_f32_16x16x32_bf16(a1h, z1l, acc[1][1], 0, 0, 0);
      acc[1][1] = __builtin_amdgcn_mfma_f32_16x16x32_bf16(a1l, z1h, acc[1][1], 0, 0, 0);
    }

    __syncthreads();                      // done reading stage buffer

    if (st + 1 < 64) {
      const char* gh = (const char*)cbh + (kofs + (st + 1) * 32) * 256 + (size_t)wv * 4096 + lane * 16;
      const char* gl_ = (const char*)cbl + (kofs + (st + 1) * 32) * 256 + (size_t)wv * 4096 + lane * 16;
      char* lh = (char*)Ah_t + wv * 4096;
      char* ll = (char*)Al_t + wv * 4096;
      #pragma unroll
      for (int i = 0; i < 4; ++i) {
        async16(gh + i * 1024, lh + i * 1024);
        async16(gl_ + i * 1024, ll + i * 1024);
      }
    }

    // distances + gated top-3 insert (dist = acc directly)
    #pragma unroll
    for (int ks = 0; ks < 2; ++ks) {
      int kbase = kb + ks * 16 + lg * 4;
      #pragma unroll
      for (int ns = 0; ns < 2; ++ns) {
        float fm = fminf(fminf(acc[ks][ns][0], acc[ks][ns][1]),
                         fminf(acc[ks][ns][2], acc[ks][ns][3]));
        if (fm < t3v[ns]) {               // sound gate
          #pragma unroll
          for (int q = 0; q < 4; ++q) {
            float v = acc[ks][ns][q];
            int kidx = kbase + q;
            bool c1 = v < t1v[ns], c2 = v < t2v[ns], c3 = v < t3v[ns];
            float n3v = c2 ? t2v[ns] : (c3 ? v : t3v[ns]);
            int   n3i = c2 ? t2i[ns] : (c3 ? kidx : t3i[ns]);
            float n2v = c1 ? t1v[ns] : (c2 ? v : t2v[ns]);
            int   n2i = c1 ? t1i[ns] : (c2 ? kidx : t2i[ns]);
            t1v[ns] = c1 ? v : t1v[ns]; t1i[ns] = c1 ? kidx : t1i[ns];
            t2v[ns] = n2v; t2i[ns] = n2i;
            t3v[ns] = n3v; t3i[ns] = n3i;
          }
        }
      }
    }
  }

  // ---- tail: lists into reused A-buffer LDS (4 lists/row x top-3)
  __syncthreads();                        // all MFMA reads of Ah_t/Al_t done
  float* tv = (float*)Ah_t;               // 64 rows x 12 floats
  int*   ti = (int*)Al_t;
  #pragma unroll
  for (int ns = 0; ns < 2; ++ns) {
    int row = nw * 32 + ns * 16 + lc;
    int base = row * 12 + lg * 3;
    tv[base + 0] = t1v[ns]; ti[base + 0] = t1i[ns];
    tv[base + 1] = t2v[ns]; ti[base + 1] = t2i[ns];
    tv[base + 2] = t3v[ns]; ti[base + 2] = t3i[ns];
  }
  __syncthreads();

  if (tid < 64) {
    int n = n0 + tid;
    float bv = 3.402823466e+38f; int bi = 0x7FFFFFFF;
    for (int e = 0; e < 12; ++e) {
      float v = tv[tid * 12 + e]; int i2 = ti[tid * 12 + e];
      if (v < bv || (v == bv && i2 < bi)) { bv = v; bi = i2; }
    }
    int ci[CAND_MAX]; int cnt = 0;
    float lim = bv + EPS_CAND;
    for (int e = 0; e < 12; ++e) {
      float v = tv[tid * 12 + e];
      if (v <= lim && cnt < CAND_MAX) {
        int x = ti[tid * 12 + e];
        int p = cnt++;
        while (p > 0 && ci[p - 1] > x) { ci[p] = ci[p - 1]; --p; }
        ci[p] = x;
      }
    }
    int kbest = ci[0];
    if (cnt > 1) {
      // exact local rescore (rare): np-exact, ascending k, strict <
      int b = n / TLEN, t = n - b * TLEN;
      const float* zr = z + (size_t)b * (DIM * TLEN) + t;
      float bestv = 0.f;
      for (int c = 0; c < cnt; ++c) {
        float dist = np_exact_dist(zr, cb + (size_t)ci[c] * DIM, x2g[n], y2g[ci[c]]);
        if (c == 0 || dist < bestv) { bestv = dist; kbest = ci[c]; }
      }
    }
    pbv[(size_t)hy * NPT + n] = bv;
    pbk[(size_t)hy * NPT + n] = kbest;
  }
}

// ---------------- merge: resolve the two k-halves per row ----------------
// |b0-b1| > EPS (>= 2*approx error) decides outright; else global argmin is
// provably one of the two exact half-winners -> rlist for exact rescore.
__global__ void merge_kernel(const float* __restrict__ pbv, const int* __restrict__ pbk,
                             int* __restrict__ idx_out, float* __restrict__ codes_out,
                             int* __restrict__ rcnt, int* __restrict__ rlist) {
  int n = blockIdx.x * 256 + threadIdx.x;
  if (n >= NPT) return;
  float b0 = pbv[n], b1 = pbv[NPT + n];
  int k0 = pbk[n], k1 = pbk[NPT + n];
  int w;
  if (b0 + EPS_CAND < b1) w = k0;
  else if (b1 + EPS_CAND < b0) w = k1;
  else {
    int slot = atomicAdd(rcnt, 1);
    if (slot < RCAP) {
      int* e = rlist + slot * 10;
      e[0] = n; e[1] = 2; e[2] = k0; e[3] = k1;   // k0 < k1 by construction
      #pragma unroll
      for (int c = 2; c < CAND_MAX; ++c) e[2 + c] = 0;
    }
    w = (b0 <= b1) ? k0 : k1;            // preliminary; rescore overwrites
  }
  idx_out[n] = w;
  codes_out[n] = (float)w;
}

// ---------------- rescore: exact np-fp32, one wave per flagged row ---------
__global__ void rescore_kernel(const float* __restrict__ z, const float* __restrict__ cb,
                               const float* __restrict__ x2g, const float* __restrict__ y2g,
                               const int* __restrict__ rcnt, const int* __restrict__ rlist,
                               int* __restrict__ idx_out, float* __restrict__ codes_out) {
  int w = (blockIdx.x * 256 + threadIdx.x) >> 6;
  int lane = threadIdx.x & 63;
  int nw = (gridDim.x * 256) >> 6;
  int total = *rcnt; if (total > RCAP) total = RCAP;
  for (int i = w; i < total; i += nw) {
    const int* e = rlist + i * 10;
    int n = e[0], cnt = e[1];
    int b = n / TLEN, t = n - b * TLEN;
    const float* zr = z + (size_t)b * (DIM * TLEN) + t;
    float dist = 3.402823466e+38f;
    int k = e[2 + (lane < cnt ? lane : 0)];
    if (lane < cnt) {
      const float* cr = cb + (size_t)k * DIM;
      float dot = 0.f;
      #pragma unroll 8
      for (int d = 0; d < DIM; ++d)
        dot = __fmaf_rn(zr[(size_t)d * TLEN], cr[d], dot);
      float tt = __fadd_rn(x2g[n], y2g[k]);
      dist = __fsub_rn(tt, __fmul_rn(2.0f, dot));
    }
    float bestv = 0.f; int kbest = 0;
    for (int c = 0; c < cnt; ++c) {
      float v = __shfl(dist, c);
      int kk = __shfl(k, c);
      if (c == 0 || v < bestv) { bestv = v; kbest = kk; }
    }
    if (lane == 0) {
      idx_out[n] = kbest;
      codes_out[n] = (float)kbest;
    }
  }
}

// ---------------- ea_scatter: one WAVE per row n — coalesced EA atomics ----
// zh/zl hold -2*z  ->  0.01*z = -0.005*(zh+zl)
__global__ void ea_scatter_kernel(const unsigned short* __restrict__ zh,
                                  const unsigned short* __restrict__ zl,
                                  const int* __restrict__ idx,
                                  float* __restrict__ ea_out,
                                  float* __restrict__ counts) {
  int n = (blockIdx.x * 256 + threadIdx.x) >> 6;
  int lane = threadIdx.x & 63;
  int k = idx[n];
  uint32_t h = *(const uint32_t*)(zh + (size_t)n * 128 + lane * 2);
  uint32_t l = *(const uint32_t*)(zl + (size_t)n * 128 + lane * 2);
  float f0 = bf2f((unsigned short)(h & 0xffffu)) + bf2f((unsigned short)(l & 0xffffu));
  float f1 = bf2f((unsigned short)(h >> 16)) + bf2f((unsigned short)(l >> 16));
  float* dst = ea_out + (size_t)k * DIM + lane * 2;
  atomicAdd(dst, -0.005f * f0);
  atomicAdd(dst + 1, -0.005f * f1);
  if (lane == 0) atomicAdd(counts + k, 1.0f);
}

// ---------------- zq_loss (tiled) ----------------
__global__ void zq_loss_kernel(const float* __restrict__ z, const float* __restrict__ cb,
                               const int* __restrict__ idx,
                               float* __restrict__ zq_out, float* __restrict__ loss_ws) {
  __shared__ float qt[64 * 132];
  const int tid = threadIdx.x;
  const int n0 = blockIdx.x * 64;
  {
    int r = tid >> 2, c = tid & 3;
    int k = idx[n0 + r];
    const float4* src = (const float4*)(cb + (size_t)k * DIM) + c * 8;
    float4* dst = (float4*)(qt + r * 132) + c * 8;
    #pragma unroll
    for (int j = 0; j < 8; ++j) dst[j] = src[j];
  }
  __syncthreads();
  int nl = tid & 63, dd = tid >> 6;
  int n = n0 + nl;
  int b = n / TLEN, t = n - b * TLEN;
  float* zqb = zq_out + (size_t)b * (DIM * TLEN) + t;
  const float* zb = z + (size_t)b * (DIM * TLEN) + t;
  float sq = 0.f;
  #pragma unroll
  for (int d = dd; d < DIM; d += 4) {
    float q = qt[nl * 132 + d];
    zqb[(size_t)d * TLEN] = q;
    float diff = zb[(size_t)d * TLEN] - q;
    sq = fmaf(diff, diff, sq);
  }
  #pragma unroll
  for (int m = 1; m <= 32; m <<= 1) sq += __shfl_xor(sq, m);
  __shared__ float ps[4];
  if ((tid & 63) == 0) ps[tid >> 6] = sq;
  __syncthreads();
  if (tid == 0) atomicAdd(loss_ws, ps[0] + ps[1] + ps[2] + ps[3]);
}

// ---------------- cs_rand ----------------
__global__ void cs_rand_kernel(const float* __restrict__ ema_cs, const float* __restrict__ counts,
                               float* __restrict__ cs0, uint32_t* __restrict__ rnd,
                               float* __restrict__ ntot) {
  int k = blockIdx.x * 256 + threadIdx.x;
  float v = 0.99f * ema_cs[k] + 0.01f * counts[k];
  cs0[k] = v;

  uint32_t o0, o1;
  threefry2x32(0u, 42u, 0u, (uint32_t)k, o0, o1);
  uint32_t bits = o0 ^ o1;
  uint32_t hi = bits >> 16, lo = bits & 0xffffu;
  const uint32_t span = 24000u, mult = 23296u;  // 2^32 % 24000
  uint32_t off = ((hi % span) * mult + (lo % span)) % span;
  rnd[k] = off;

  float s = v;
  #pragma unroll
  for (int m = 1; m <= 32; m <<= 1) s += __shfl_xor(s, m);
  __shared__ float ps[4];
  if ((threadIdx.x & 63) == 0) ps[threadIdx.x >> 6] = s;
  __syncthreads();
  if (threadIdx.x == 0) atomicAdd(ntot, ps[0] + ps[1] + ps[2] + ps[3]);
}

// ---------------- finalize ----------------
__global__ void finalize_kernel(const float* __restrict__ z, const float* __restrict__ cs0_ws,
                                const uint32_t* __restrict__ rnd,
                                const float* __restrict__ ntot_ws, const float* __restrict__ loss_ws,
                                float* __restrict__ out) {
  int i = blockIdx.x * 256 + threadIdx.x;   // i < KD
  int k = i >> 7, d = i & (DIM - 1);
  float cs0 = cs0_ws[k];
  float ntot = *ntot_ws;
  float* ea = out + OFF_EA;
  float ea0 = ea[i];
  float csz = (cs0 + 1e-5f) / (ntot + (float)KCB * 1e-5f) * ntot;
  float embed = ea0 / fmaxf(csz, 1e-12f);
  bool dead = cs0 < 2.0f;
  uint32_t rn = rnd[k];
  int bb = (int)(rn / TLEN), tt = (int)(rn % TLEN);
  float sampled = z[(size_t)bb * (DIM * TLEN) + (size_t)d * TLEN + tt];
  out[OFF_CB + i] = dead ? sampled : embed;
  ea[i] = dead ? sampled : ea0;
  if (d == 0) out[OFF_CS + k] = dead ? 1.0f : cs0;
  if (i == 0) out[OFF_LOSS] = (*loss_ws) * (1.0f / (float)BDT);
}

extern "C" void kernel_launch(void* const* d_in, const int* in_sizes, int n_in,
                              void* d_out, int out_size, void* d_ws, size_t ws_size,
                              hipStream_t stream) {
  const float* z      = (const float*)d_in[0];
  const float* cb     = (const float*)d_in[1];
  const float* ema_cs = (const float*)d_in[2];
  const float* ema_ea = (const float*)d_in[3];
  float* out = (float*)d_out;
  float* wsf = (float*)d_ws;

  unsigned short* zh  = (unsigned short*)(out + OUT_ZH);
  unsigned short* zl  = (unsigned short*)(out + OUT_ZL);
  unsigned short* cbh = (unsigned short*)(out + OUT_CBH);
  unsigned short* cbl = (unsigned short*)(out + OUT_CBL);

  hipMemsetAsync(d_ws, 0, (size_t)(16 + 4096) * sizeof(float), stream);
  hipMemsetAsync(wsf + WS_RCNT, 0, 16 * sizeof(float), stream);

  prep_cb_kernel<<<KCB / 256, 256, 0, stream>>>(cb, cbh, cbl, wsf + WS_Y2);
  prep_z_kernel<<<NPT / 64, 256, 0, stream>>>(z, zh, zl, wsf + WS_X2);
  ea_init_kernel<<<KD / 256, 256, 0, stream>>>(ema_ea, out + OFF_EA);

  dim3 agrid(NPT / 64, 2);
  mfma_argmin_kernel<<<agrid, 128, 0, stream>>>(zh, zl, cbh, cbl,
                                                wsf + WS_Y2, wsf + WS_X2,
                                                z, cb,
                                                wsf + WS_PBV, (int*)(wsf + WS_PBK));
  merge_kernel<<<(NPT + 255) / 256, 256, 0, stream>>>(wsf + WS_PBV, (int*)(wsf + WS_PBK),
                                                      (int*)(wsf + WS_IDX), out + OFF_CODES,
                                                      (int*)(wsf + WS_RCNT), (int*)(wsf + WS_RLIST));
  rescore_kernel<<<64, 256, 0, stream>>>(z, cb, wsf + WS_X2, wsf + WS_Y2,
                                         (const int*)(wsf + WS_RCNT), (const int*)(wsf + WS_RLIST),
                                         (int*)(wsf + WS_IDX), out + OFF_CODES);

  // ea_scatter reads zh/zl (z_q region) -> MUST run before zq_loss overwrites it
  ea_scatter_kernel<<<NPT * 64 / 256, 256, 0, stream>>>(zh, zl, (int*)(wsf + WS_IDX),
                                                        out + OFF_EA, wsf + WS_COUNTS);
  zq_loss_kernel<<<NPT / 64, 256, 0, stream>>>(z, cb, (int*)(wsf + WS_IDX),
                                               out + OFF_ZQ, wsf + WS_LOSS);
  cs_rand_kernel<<<KCB / 256, 256, 0, stream>>>(ema_cs, wsf + WS_COUNTS,
                                                wsf + WS_CS0, (uint32_t*)(wsf + WS_RAND),
                                                wsf + WS_NTOT);
  finalize_kernel<<<KD / 256, 256, 0, stream>>>(z, wsf + WS_CS0, (uint32_t*)(wsf + WS_RAND),
                                                wsf + WS_NTOT, wsf + WS_LOSS, out);
}

// Round 19
// 224.650 us; speedup vs baseline: 1.0979x; 1.0979x over previous
//
#include <hip/hip_runtime.h>
#include <stdint.h>

// Problem constants
#define KCB 4096
#define DIM 128
#define BSZ 8
#define TLEN 3000
#define NPT 24000            // BSZ*TLEN
#define KD (KCB*DIM)         // 524288
#define BDT (BSZ*DIM*TLEN)   // 3072000

// Output layout (floats, concatenated in reference return order)
#define OFF_ZQ    0
#define OFF_CODES 3072000
#define OFF_LOSS  3096000
#define OFF_CB    3096001
#define OFF_CS    3620289
#define OFF_EA    3624385

// Big scratch in d_out regions that are dead until later kernels:
//   zh/zl  -> z_q region (holds -2*z split; z_q written by zq_loss later)
//   cbh/cbl-> new_codebook region (PRE-SWIZZLED chunks; finalize writes LAST)
#define OUT_ZH    0
#define OUT_ZL    1536000
#define OUT_CBH   3096004
#define OUT_CBL   3358148

// Workspace layout (float units). RCNT lives in the header so ONE memset
// covers {loss, ntot, rcnt, counts}.
#define WS_LOSS   0
#define WS_NTOT   1
#define WS_RCNT   2
#define WS_COUNTS 16                     // 4096
#define WS_Y2     (WS_COUNTS + 4096)     // 4096
#define WS_X2     (WS_Y2 + 4096)         // 24000
#define WS_CS0    (WS_X2 + 24000)        // 4096
#define WS_RAND   (WS_CS0 + 4096)        // uint32[4096]
#define WS_IDX    (WS_RAND + 4096)       // int32[24000]
#define WS_RLIST  (WS_IDX + 24000)       // int32[RCAP*10]
#define RCAP      8192

#define EPS_CAND 2e-3f
#define CAND_MAX 8

// fused-prep block ranges
#define NB_CB  16      // prep_cb: 4096 k / 256
#define NB_Z   375     // prep_z: 24000 n / 64
#define NB_EA  2048    // ea_init: KD / 256
// fused zq/cs block ranges
#define NB_ZQ  375

typedef __attribute__((ext_vector_type(8))) short bf16x8;
typedef __attribute__((ext_vector_type(4))) float f32x4;
typedef __attribute__((ext_vector_type(4))) int i32x4;

__device__ __forceinline__ unsigned short f2bf(float f) {
  uint32_t u = __float_as_uint(f);
  uint32_t r = (u + 0x7FFFu + ((u >> 16) & 1u)) >> 16;   // RNE
  return (unsigned short)r;
}
__device__ __forceinline__ float bf2f(unsigned short h) {
  return __uint_as_float(((uint32_t)h) << 16);
}

// async global->LDS DMA, 16 B per lane; LDS dest = wave-uniform base + lane*16
__device__ __forceinline__ void async16(const void* g, void* l) {
  __builtin_amdgcn_global_load_lds(
      (const __attribute__((address_space(1))) void*)g,
      (__attribute__((address_space(3))) void*)l, 16, 0, 0);
}

// ---------------- threefry2x32-20 (JAX-compatible) ----------------
__device__ __forceinline__ void threefry2x32(uint32_t k0, uint32_t k1,
                                             uint32_t x0, uint32_t x1,
                                             uint32_t& o0, uint32_t& o1) {
  const uint32_t ks0 = k0, ks1 = k1, ks2 = k0 ^ k1 ^ 0x1BD11BDAu;
  const int r0[4] = {13, 15, 26, 6};
  const int r1[4] = {17, 29, 16, 24};
  x0 += ks0; x1 += ks1;
  #pragma unroll
  for (int i = 0; i < 5; ++i) {
    #pragma unroll
    for (int j = 0; j < 4; ++j) {
      int r = (i & 1) ? r1[j] : r0[j];
      x0 += x1;
      x1 = (x1 << r) | (x1 >> (32 - r));
      x1 ^= x0;
    }
    uint32_t ia = (uint32_t)((i + 1) % 3), ib = (uint32_t)((i + 2) % 3);
    uint32_t a = (ia == 0) ? ks0 : (ia == 1) ? ks1 : ks2;
    uint32_t b = (ib == 0) ? ks0 : (ib == 1) ? ks1 : ks2;
    x0 += a;
    x1 += b + (uint32_t)(i + 1);
  }
  o0 = x0; o1 = x1;
}

// numpy pairwise sum-of-squares, n=128
__device__ __forceinline__ float np_sumsq_128(const float* __restrict__ v) {
  float r[8];
  #pragma unroll
  for (int j = 0; j < 8; ++j) r[j] = __fmul_rn(v[j], v[j]);
  #pragma unroll
  for (int i = 8; i < DIM; i += 8) {
    #pragma unroll
    for (int j = 0; j < 8; ++j)
      r[j] = __fadd_rn(r[j], __fmul_rn(v[i + j], v[i + j]));
  }
  return __fadd_rn(__fadd_rn(__fadd_rn(r[0], r[1]), __fadd_rn(r[2], r[3])),
                   __fadd_rn(__fadd_rn(r[4], r[5]), __fadd_rn(r[6], r[7])));
}

// ---------------- fused prep: prep_cb | prep_z | ea_init -------------------
// Independent writes; block-range partitioned. Saves 2 launches.
__global__ void prep_all_kernel(const float* __restrict__ z, const float* __restrict__ cb,
                                unsigned short* __restrict__ zh, unsigned short* __restrict__ zl,
                                float* __restrict__ x2,
                                unsigned short* __restrict__ cbh, unsigned short* __restrict__ cbl,
                                float* __restrict__ y2,
                                const float* __restrict__ ema_ea, float* __restrict__ out_ea) {
  __shared__ float zt[64 * 132];
  const int bid = blockIdx.x;
  const int tid = threadIdx.x;

  if (bid < NB_CB) {
    // ---- prep_cb: bf16 hi/lo, chunks PRE-SWIZZLED (c ^= k&7), np-exact y2
    int k = bid * 256 + tid;
    const float4* row4 = (const float4*)(cb + (size_t)k * DIM);
    float racc[8];
    #pragma unroll
    for (int j = 0; j < 8; ++j) racc[j] = 0.f;
    #pragma unroll 4
    for (int c2 = 0; c2 < 16; ++c2) {
      float4 a = row4[c2 * 2], b = row4[c2 * 2 + 1];
      float f[8] = {a.x, a.y, a.z, a.w, b.x, b.y, b.z, b.w};
      i32x4 wh, wl;
      #pragma unroll
      for (int q = 0; q < 4; ++q) {
        float f0 = f[q * 2], f1 = f[q * 2 + 1];
        unsigned short h0 = f2bf(f0), h1 = f2bf(f1);
        unsigned short l0 = f2bf(f0 - bf2f(h0)), l1 = f2bf(f1 - bf2f(h1));
        wh[q] = (int)((uint32_t)h0 | ((uint32_t)h1 << 16));
        wl[q] = (int)((uint32_t)l0 | ((uint32_t)l1 << 16));
      }
      int cs = c2 ^ (k & 7);
      *(i32x4*)(cbh + (size_t)k * DIM + cs * 8) = wh;
      *(i32x4*)(cbl + (size_t)k * DIM + cs * 8) = wl;
      #pragma unroll
      for (int j = 0; j < 8; ++j)
        racc[j] = __fadd_rn(racc[j], __fmul_rn(f[j], f[j]));
    }
    y2[k] = __fadd_rn(__fadd_rn(__fadd_rn(racc[0], racc[1]), __fadd_rn(racc[2], racc[3])),
                      __fadd_rn(__fadd_rn(racc[4], racc[5]), __fadd_rn(racc[6], racc[7])));
  } else if (bid < NB_CB + NB_Z) {
    // ---- prep_z: transpose z -> bf16 hi/lo of (-2*z) + np-exact x2
    const int n0 = (bid - NB_CB) * 64;
    {
      int nl = tid & 63, dd = tid >> 6;
      int n = n0 + nl;
      int b = n / TLEN, t = n - b * TLEN;
      const float* zbase = z + (size_t)b * (DIM * TLEN) + t;
      #pragma unroll
      for (int d = dd; d < DIM; d += 4) zt[nl * 132 + d] = zbase[(size_t)d * TLEN];
    }
    __syncthreads();
    if (tid < 64) x2[n0 + tid] = np_sumsq_128(zt + tid * 132);   // on ORIGINAL z

    int r = tid >> 2, d0 = (tid & 3) * 32;
    const float* src = zt + r * 132 + d0;
    size_t base = (size_t)(n0 + r) * 128 + d0;
    #pragma unroll
    for (int c = 0; c < 4; ++c) {
      i32x4 wh, wl;
      #pragma unroll
      for (int q = 0; q < 4; ++q) {
        float f0 = -2.0f * src[c * 8 + q * 2], f1 = -2.0f * src[c * 8 + q * 2 + 1];
        unsigned short h0 = f2bf(f0), h1 = f2bf(f1);
        unsigned short l0 = f2bf(f0 - bf2f(h0)), l1 = f2bf(f1 - bf2f(h1));
        wh[q] = (int)((uint32_t)h0 | ((uint32_t)h1 << 16));
        wl[q] = (int)((uint32_t)l0 | ((uint32_t)l1 << 16));
      }
      *(i32x4*)(zh + base + c * 8) = wh;
      *(i32x4*)(zl + base + c * 8) = wl;
    }
  } else {
    // ---- ea_init
    int i = (bid - NB_CB - NB_Z) * 256 + tid;
    out_ea[i] = 0.99f * ema_ea[i];
  }
}

// ---------------- MFMA argmin: 64n x 64k tiles, 2x2 waves of 32k x 32n -----
// R17-verified: 375 blocks x 256 thr, DMA-staged A tiles, dist = acc
// (z pre-scaled -2, y2 in C-init), gated per-lane top-3, in-block exact-
// rescore flag list. 76 KB LDS -> 2 blocks/CU.
__launch_bounds__(256)
__global__ void mfma_argmin_kernel(const unsigned short* __restrict__ zh,
                                   const unsigned short* __restrict__ zl,
                                   const unsigned short* __restrict__ cbh,
                                   const unsigned short* __restrict__ cbl,
                                   const float* __restrict__ y2g,
                                   const float* __restrict__ x2g,
                                   const float* __restrict__ z,
                                   const float* __restrict__ cb,
                                   int* __restrict__ idx_out,
                                   float* __restrict__ codes_out,
                                   int* __restrict__ rcnt,
                                   int* __restrict__ rlist) {
  __shared__ alignas(16) unsigned short zh_t[64 * 128];   // 16 KB, swizzled
  __shared__ alignas(16) unsigned short zl_t[64 * 128];   // 16 KB
  __shared__ alignas(16) unsigned short Ah_t[64 * 128];   // 16 KB, swizzled-by-source
  __shared__ alignas(16) unsigned short Al_t[64 * 128];   // 16 KB
  __shared__ float tv[64 * 24];                           // 6 KB
  __shared__ int   ti[64 * 24];                           // 6 KB

  const int tid = threadIdx.x;
  const int wv = tid >> 6, lane = tid & 63;
  const int kw = wv & 1, nw = wv >> 1;     // 2x2 wave grid
  const int lg = lane >> 4, lc = lane & 15;
  const int n0 = blockIdx.x * 64;

  // issue tile-0 DMA first (overlaps with z staging)
  {
    const char* gh = (const char*)cbh + (size_t)(wv * 4) * 1024 + lane * 16;
    const char* gl_ = (const char*)cbl + (size_t)(wv * 4) * 1024 + lane * 16;
    char* lh = (char*)Ah_t + wv * 4096;
    char* ll = (char*)Al_t + wv * 4096;
    #pragma unroll
    for (int i = 0; i < 4; ++i) {
      async16(gh + i * 1024, lh + i * 1024);
      async16(gl_ + i * 1024, ll + i * 1024);
    }
  }

  // stage 64 z rows hi/lo into LDS once (chunk = 16B; swizzle cc = c ^ (r&7))
  {
    int r = tid >> 2, c0 = (tid & 3) * 4;
    const i32x4* gzh = (const i32x4*)(zh + (size_t)(n0 + r) * 128);
    const i32x4* gzl = (const i32x4*)(zl + (size_t)(n0 + r) * 128);
    #pragma unroll
    for (int c = 0; c < 4; ++c) {
      int cc = (c0 + c) ^ (r & 7);
      ((i32x4*)zh_t)[r * 16 + cc] = gzh[c0 + c];
      ((i32x4*)zl_t)[r * 16 + cc] = gzl[c0 + c];
    }
  }

  float t1v[2], t2v[2], t3v[2];
  int   t1i[2], t2i[2], t3i[2];
  #pragma unroll
  for (int ns = 0; ns < 2; ++ns) {
    t1v[ns] = t2v[ns] = t3v[ns] = 3.402823466e+38f;
    t1i[ns] = t2i[ns] = t3i[ns] = 0x7FFFFFFF;
  }

  const int arow0 = kw * 32 + lc,  arow1 = kw * 32 + 16 + lc;   // A rows (k)
  const int zrow0 = nw * 32 + lc,  zrow1 = nw * 32 + 16 + lc;   // z rows (n)

  for (int tile = 0; tile < 64; ++tile) {
    asm volatile("s_waitcnt vmcnt(0)" ::: "memory");
    __syncthreads();                      // tile data ready

    const int kb = tile * 64 + kw * 32;
    float4 y40 = *(const float4*)(y2g + kb + lg * 4);
    float4 y41 = *(const float4*)(y2g + kb + 16 + lg * 4);
    f32x4 acc[2][2];                      // [ks][ns]
    #pragma unroll
    for (int ns = 0; ns < 2; ++ns) {
      acc[0][ns][0] = y40.x; acc[0][ns][1] = y40.y; acc[0][ns][2] = y40.z; acc[0][ns][3] = y40.w;
      acc[1][ns][0] = y41.x; acc[1][ns][1] = y41.y; acc[1][ns][2] = y41.z; acc[1][ns][3] = y41.w;
    }

    #pragma unroll
    for (int ds = 0; ds < 4; ++ds) {
      int cA0 = (ds * 4 + lg) ^ (arow0 & 7);
      int cA1 = (ds * 4 + lg) ^ (arow1 & 7);
      bf16x8 a0h = *(const bf16x8*)&Ah_t[arow0 * 128 + cA0 * 8];
      bf16x8 a0l = *(const bf16x8*)&Al_t[arow0 * 128 + cA0 * 8];
      bf16x8 a1h = *(const bf16x8*)&Ah_t[arow1 * 128 + cA1 * 8];
      bf16x8 a1l = *(const bf16x8*)&Al_t[arow1 * 128 + cA1 * 8];
      int cz0 = (ds * 4 + lg) ^ (zrow0 & 7);
      int cz1 = (ds * 4 + lg) ^ (zrow1 & 7);
      bf16x8 z0h = *(const bf16x8*)&zh_t[zrow0 * 128 + cz0 * 8];
      bf16x8 z0l = *(const bf16x8*)&zl_t[zrow0 * 128 + cz0 * 8];
      bf16x8 z1h = *(const bf16x8*)&zh_t[zrow1 * 128 + cz1 * 8];
      bf16x8 z1l = *(const bf16x8*)&zl_t[zrow1 * 128 + cz1 * 8];
      acc[0][0] = __builtin_amdgcn_mfma_f32_16x16x32_bf16(a0h, z0h, acc[0][0], 0, 0, 0);
      acc[0][0] = __builtin_amdgcn_mfma_f32_16x16x32_bf16(a0h, z0l, acc[0][0], 0, 0, 0);
      acc[0][0] = __builtin_amdgcn_mfma_f32_16x16x32_bf16(a0l, z0h, acc[0][0], 0, 0, 0);
      acc[0][1] = __builtin_amdgcn_mfma_f32_16x16x32_bf16(a0h, z1h, acc[0][1], 0, 0, 0);
      acc[0][1] = __builtin_amdgcn_mfma_f32_16x16x32_bf16(a0h, z1l, acc[0][1], 0, 0, 0);
      acc[0][1] = __builtin_amdgcn_mfma_f32_16x16x32_bf16(a0l, z1h, acc[0][1], 0, 0, 0);
      acc[1][0] = __builtin_amdgcn_mfma_f32_16x16x32_bf16(a1h, z0h, acc[1][0], 0, 0, 0);
      acc[1][0] = __builtin_amdgcn_mfma_f32_16x16x32_bf16(a1h, z0l, acc[1][0], 0, 0, 0);
      acc[1][0] = __builtin_amdgcn_mfma_f32_16x16x32_bf16(a1l, z0h, acc[1][0], 0, 0, 0);
      acc[1][1] = __builtin_amdgcn_mfma_f32_16x16x32_bf16(a1h, z1h, acc[1][1], 0, 0, 0);
      acc[1][1] = __builtin_amdgcn_mfma_f32_16x16x32_bf16(a1h, z1l, acc[1][1], 0, 0, 0);
      acc[1][1] = __builtin_amdgcn_mfma_f32_16x16x32_bf16(a1l, z1h, acc[1][1], 0, 0, 0);
    }

    __syncthreads();                      // done reading tile buffer

    // issue next tile's DMA (hides under dist/insert VALU + co-resident block)
    if (tile + 1 < 64) {
      const char* gh = (const char*)cbh + (size_t)(tile + 1) * 16384 + (size_t)(wv * 4) * 1024 + lane * 16;
      const char* gl_ = (const char*)cbl + (size_t)(tile + 1) * 16384 + (size_t)(wv * 4) * 1024 + lane * 16;
      char* lh = (char*)Ah_t + wv * 4096;
      char* ll = (char*)Al_t + wv * 4096;
      #pragma unroll
      for (int i = 0; i < 4; ++i) {
        async16(gh + i * 1024, lh + i * 1024);
        async16(gl_ + i * 1024, ll + i * 1024);
      }
    }

    // distances + gated top-3 insert (dist = acc directly)
    #pragma unroll
    for (int ks = 0; ks < 2; ++ks) {
      int kbase = kb + ks * 16 + lg * 4;
      #pragma unroll
      for (int ns = 0; ns < 2; ++ns) {
        float fm = fminf(fminf(acc[ks][ns][0], acc[ks][ns][1]),
                         fminf(acc[ks][ns][2], acc[ks][ns][3]));
        if (fm < t3v[ns]) {               // sound gate
          #pragma unroll
          for (int q = 0; q < 4; ++q) {
            float v = acc[ks][ns][q];
            int kidx = kbase + q;
            bool c1 = v < t1v[ns], c2 = v < t2v[ns], c3 = v < t3v[ns];
            float n3v = c2 ? t2v[ns] : (c3 ? v : t3v[ns]);
            int   n3i = c2 ? t2i[ns] : (c3 ? kidx : t3i[ns]);
            float n2v = c1 ? t1v[ns] : (c2 ? v : t2v[ns]);
            int   n2i = c1 ? t1i[ns] : (c2 ? kidx : t2i[ns]);
            t1v[ns] = c1 ? v : t1v[ns]; t1i[ns] = c1 ? kidx : t1i[ns];
            t2v[ns] = n2v; t2i[ns] = n2i;
            t3v[ns] = n3v; t3i[ns] = n3i;
          }
        }
      }
    }
  }

  // ---- tail: 8 lists/row (2 kw x 4 lg) x top-3 -> candidates -> rescore
  #pragma unroll
  for (int ns = 0; ns < 2; ++ns) {
    int row = nw * 32 + ns * 16 + lc;
    int base = row * 24 + (kw * 4 + lg) * 3;
    tv[base + 0] = t1v[ns]; ti[base + 0] = t1i[ns];
    tv[base + 1] = t2v[ns]; ti[base + 1] = t2i[ns];
    tv[base + 2] = t3v[ns]; ti[base + 2] = t3i[ns];
  }
  __syncthreads();

  if (tid < 64) {
    int n = n0 + tid;
    float bv = 3.402823466e+38f; int bi = 0x7FFFFFFF;
    for (int e = 0; e < 24; ++e) {
      float v = tv[tid * 24 + e]; int i2 = ti[tid * 24 + e];
      if (v < bv || (v == bv && i2 < bi)) { bv = v; bi = i2; }
    }
    int ci[CAND_MAX]; int cnt = 0;
    float lim = bv + EPS_CAND;
    for (int e = 0; e < 24; ++e) {
      float v = tv[tid * 24 + e];
      if (v <= lim && cnt < CAND_MAX) {
        int x = ti[tid * 24 + e];
        int p = cnt++;
        while (p > 0 && ci[p - 1] > x) { ci[p] = ci[p - 1]; --p; }
        ci[p] = x;
      }
    }
    if (cnt == 1) {
      idx_out[n] = ci[0];
      codes_out[n] = (float)ci[0];
    } else {
      int slot = atomicAdd(rcnt, 1);
      if (slot < RCAP) {
        int* e = rlist + slot * 10;
        e[0] = n; e[1] = cnt;
        for (int c = 0; c < CAND_MAX; ++c) e[2 + c] = (c < cnt) ? ci[c] : 0;
        idx_out[n] = ci[0];              // preliminary; rescore overwrites
        codes_out[n] = (float)ci[0];
      } else {
        int b = n / TLEN, t = n - b * TLEN;
        const float* zr = z + (size_t)b * (DIM * TLEN) + t;
        float bestv = 0.f; int kbest = ci[0];
        for (int c = 0; c < cnt; ++c) {
          int k = ci[c];
          const float* cr = cb + (size_t)k * DIM;
          float dot = 0.f;
          for (int d = 0; d < DIM; ++d)
            dot = __fmaf_rn(zr[(size_t)d * TLEN], cr[d], dot);
          float tt = __fadd_rn(x2g[n], y2g[k]);
          float dist = __fsub_rn(tt, __fmul_rn(2.0f, dot));
          if (c == 0 || dist < bestv) { bestv = dist; kbest = k; }
        }
        idx_out[n] = kbest;
        codes_out[n] = (float)kbest;
      }
    }
  }
}

// ---------------- rescore: exact np-fp32, one wave per flagged row ---------
__global__ void rescore_kernel(const float* __restrict__ z, const float* __restrict__ cb,
                               const float* __restrict__ x2g, const float* __restrict__ y2g,
                               const int* __restrict__ rcnt, const int* __restrict__ rlist,
                               int* __restrict__ idx_out, float* __restrict__ codes_out) {
  int w = (blockIdx.x * 256 + threadIdx.x) >> 6;
  int lane = threadIdx.x & 63;
  int nw = (gridDim.x * 256) >> 6;
  int total = *rcnt; if (total > RCAP) total = RCAP;
  for (int i = w; i < total; i += nw) {
    const int* e = rlist + i * 10;
    int n = e[0], cnt = e[1];
    int b = n / TLEN, t = n - b * TLEN;
    const float* zr = z + (size_t)b * (DIM * TLEN) + t;
    float dist = 3.402823466e+38f;
    int k = e[2 + (lane < cnt ? lane : 0)];
    if (lane < cnt) {
      const float* cr = cb + (size_t)k * DIM;
      float dot = 0.f;
      #pragma unroll 8
      for (int d = 0; d < DIM; ++d)
        dot = __fmaf_rn(zr[(size_t)d * TLEN], cr[d], dot);
      float tt = __fadd_rn(x2g[n], y2g[k]);
      dist = __fsub_rn(tt, __fmul_rn(2.0f, dot));
    }
    float bestv = 0.f; int kbest = 0;
    for (int c = 0; c < cnt; ++c) {
      float v = __shfl(dist, c);
      int kk = __shfl(k, c);
      if (c == 0 || v < bestv) { bestv = v; kbest = kk; }
    }
    if (lane == 0) {
      idx_out[n] = kbest;
      codes_out[n] = (float)kbest;
    }
  }
}

// ---------------- ea_scatter: one WAVE per row n — coalesced EA atomics ----
// zh/zl hold -2*z  ->  0.01*z = -0.005*(zh+zl)
__global__ void ea_scatter_kernel(const unsigned short* __restrict__ zh,
                                  const unsigned short* __restrict__ zl,
                                  const int* __restrict__ idx,
                                  float* __restrict__ ea_out,
                                  float* __restrict__ counts) {
  int n = (blockIdx.x * 256 + threadIdx.x) >> 6;
  int lane = threadIdx.x & 63;
  int k = idx[n];
  uint32_t h = *(const uint32_t*)(zh + (size_t)n * 128 + lane * 2);
  uint32_t l = *(const uint32_t*)(zl + (size_t)n * 128 + lane * 2);
  float f0 = bf2f((unsigned short)(h & 0xffffu)) + bf2f((unsigned short)(l & 0xffffu));
  float f1 = bf2f((unsigned short)(h >> 16)) + bf2f((unsigned short)(l >> 16));
  float* dst = ea_out + (size_t)k * DIM + lane * 2;
  atomicAdd(dst, -0.005f * f0);
  atomicAdd(dst + 1, -0.005f * f1);
  if (lane == 0) atomicAdd(counts + k, 1.0f);
}

// ---------------- fused zq_loss | cs_rand (both depend only on ea_scatter) -
__global__ void zq_cs_kernel(const float* __restrict__ z, const float* __restrict__ cb,
                             const int* __restrict__ idx,
                             float* __restrict__ zq_out, float* __restrict__ loss_ws,
                             const float* __restrict__ ema_cs, const float* __restrict__ counts,
                             float* __restrict__ cs0, uint32_t* __restrict__ rnd,
                             float* __restrict__ ntot) {
  __shared__ float qt[64 * 132];
  __shared__ float ps[4];
  const int bid = blockIdx.x;
  const int tid = threadIdx.x;

  if (bid < NB_ZQ) {
    // ---- zq_loss (tiled)
    const int n0 = bid * 64;
    {
      int r = tid >> 2, c = tid & 3;
      int k = idx[n0 + r];
      const float4* src = (const float4*)(cb + (size_t)k * DIM) + c * 8;
      float4* dst = (float4*)(qt + r * 132) + c * 8;
      #pragma unroll
      for (int j = 0; j < 8; ++j) dst[j] = src[j];
    }
    __syncthreads();
    int nl = tid & 63, dd = tid >> 6;
    int n = n0 + nl;
    int b = n / TLEN, t = n - b * TLEN;
    float* zqb = zq_out + (size_t)b * (DIM * TLEN) + t;
    const float* zb = z + (size_t)b * (DIM * TLEN) + t;
    float sq = 0.f;
    #pragma unroll
    for (int d = dd; d < DIM; d += 4) {
      float q = qt[nl * 132 + d];
      zqb[(size_t)d * TLEN] = q;
      float diff = zb[(size_t)d * TLEN] - q;
      sq = fmaf(diff, diff, sq);
    }
    #pragma unroll
    for (int m = 1; m <= 32; m <<= 1) sq += __shfl_xor(sq, m);
    if ((tid & 63) == 0) ps[tid >> 6] = sq;
    __syncthreads();
    if (tid == 0) atomicAdd(loss_ws, ps[0] + ps[1] + ps[2] + ps[3]);
  } else {
    // ---- cs_rand
    int k = (bid - NB_ZQ) * 256 + tid;
    float v = 0.99f * ema_cs[k] + 0.01f * counts[k];
    cs0[k] = v;

    uint32_t o0, o1;
    threefry2x32(0u, 42u, 0u, (uint32_t)k, o0, o1);
    uint32_t bits = o0 ^ o1;
    uint32_t hi = bits >> 16, lo = bits & 0xffffu;
    const uint32_t span = 24000u, mult = 23296u;  // 2^32 % 24000
    uint32_t off = ((hi % span) * mult + (lo % span)) % span;
    rnd[k] = off;

    float s = v;
    #pragma unroll
    for (int m = 1; m <= 32; m <<= 1) s += __shfl_xor(s, m);
    if ((tid & 63) == 0) ps[tid >> 6] = s;
    __syncthreads();
    if (tid == 0) atomicAdd(ntot, ps[0] + ps[1] + ps[2] + ps[3]);
  }
}

// ---------------- finalize ----------------
__global__ void finalize_kernel(const float* __restrict__ z, const float* __restrict__ cs0_ws,
                                const uint32_t* __restrict__ rnd,
                                const float* __restrict__ ntot_ws, const float* __restrict__ loss_ws,
                                float* __restrict__ out) {
  int i = blockIdx.x * 256 + threadIdx.x;   // i < KD
  int k = i >> 7, d = i & (DIM - 1);
  float cs0 = cs0_ws[k];
  float ntot = *ntot_ws;
  float* ea = out + OFF_EA;
  float ea0 = ea[i];
  float csz = (cs0 + 1e-5f) / (ntot + (float)KCB * 1e-5f) * ntot;
  float embed = ea0 / fmaxf(csz, 1e-12f);
  bool dead = cs0 < 2.0f;
  uint32_t rn = rnd[k];
  int bb = (int)(rn / TLEN), tt = (int)(rn % TLEN);
  float sampled = z[(size_t)bb * (DIM * TLEN) + (size_t)d * TLEN + tt];
  out[OFF_CB + i] = dead ? sampled : embed;
  ea[i] = dead ? sampled : ea0;
  if (d == 0) out[OFF_CS + k] = dead ? 1.0f : cs0;
  if (i == 0) out[OFF_LOSS] = (*loss_ws) * (1.0f / (float)BDT);
}

extern "C" void kernel_launch(void* const* d_in, const int* in_sizes, int n_in,
                              void* d_out, int out_size, void* d_ws, size_t ws_size,
                              hipStream_t stream) {
  const float* z      = (const float*)d_in[0];
  const float* cb     = (const float*)d_in[1];
  const float* ema_cs = (const float*)d_in[2];
  const float* ema_ea = (const float*)d_in[3];
  float* out = (float*)d_out;
  float* wsf = (float*)d_ws;

  unsigned short* zh  = (unsigned short*)(out + OUT_ZH);
  unsigned short* zl  = (unsigned short*)(out + OUT_ZL);
  unsigned short* cbh = (unsigned short*)(out + OUT_CBH);
  unsigned short* cbl = (unsigned short*)(out + OUT_CBL);

  // zero loss, ntot, rcnt, counts in ONE memset
  hipMemsetAsync(d_ws, 0, (size_t)(16 + 4096) * sizeof(float), stream);

  prep_all_kernel<<<NB_CB + NB_Z + NB_EA, 256, 0, stream>>>(
      z, cb, zh, zl, wsf + WS_X2, cbh, cbl, wsf + WS_Y2, ema_ea, out + OFF_EA);

  mfma_argmin_kernel<<<NPT / 64, 256, 0, stream>>>(zh, zl, cbh, cbl,
                                                   wsf + WS_Y2, wsf + WS_X2,
                                                   z, cb,
                                                   (int*)(wsf + WS_IDX), out + OFF_CODES,
                                                   (int*)(wsf + WS_RCNT), (int*)(wsf + WS_RLIST));
  rescore_kernel<<<64, 256, 0, stream>>>(z, cb, wsf + WS_X2, wsf + WS_Y2,
                                         (const int*)(wsf + WS_RCNT), (const int*)(wsf + WS_RLIST),
                                         (int*)(wsf + WS_IDX), out + OFF_CODES);

  // ea_scatter reads zh/zl (z_q region) -> MUST run before zq writes there
  ea_scatter_kernel<<<NPT * 64 / 256, 256, 0, stream>>>(zh, zl, (int*)(wsf + WS_IDX),
                                                        out + OFF_EA, wsf + WS_COUNTS);
  zq_cs_kernel<<<NB_ZQ + 16, 256, 0, stream>>>(z, cb, (int*)(wsf + WS_IDX),
                                               out + OFF_ZQ, wsf + WS_LOSS,
                                               ema_cs, wsf + WS_COUNTS,
                                               wsf + WS_CS0, (uint32_t*)(wsf + WS_RAND),
                                               wsf + WS_NTOT);
  finalize_kernel<<<KD / 256, 256, 0, stream>>>(z, wsf + WS_CS0, (uint32_t*)(wsf + WS_RAND),
                                                wsf + WS_NTOT, wsf + WS_LOSS, out);
}